// Round 2
// baseline (114.730 us; speedup 1.0000x reference)
//
#include <hip/hip_runtime.h>

#define BB 32
#define MM 512
#define SS 10
#define VV 32000
#define DD 128
#define HOPS 3
#define BM (BB * MM)

// ====================== PRIMARY PATH ======================
// E[t][bm][d] = sum_s C[t][story[bm][s]][d], all 4 tables in one pass.
// Block 0 additionally copies hidden -> u.
__global__ __launch_bounds__(256) void precompute_E(const int* __restrict__ story,
                                                    const float* __restrict__ C,
                                                    float* __restrict__ E,
                                                    const float* __restrict__ hidden,
                                                    float* __restrict__ u) {
    if (blockIdx.x == 0) {
        for (int i = threadIdx.x; i < BB * DD; i += 256) u[i] = hidden[i];
    }
    int wid = (blockIdx.x * 256 + threadIdx.x) >> 6;   // 0 .. BM-1
    int lane = threadIdx.x & 63;
    if (wid >= BM) return;
    const int* st = story + (size_t)wid * SS;
    int tok[SS];
#pragma unroll
    for (int s = 0; s < SS; ++s) tok[s] = st[s];
#pragma unroll
    for (int t = 0; t < HOPS + 1; ++t) {
        float ax = 0.f, ay = 0.f;
#pragma unroll
        for (int s = 0; s < SS; ++s) {
            const float2 v = ((const float2*)(C + ((size_t)t * VV + tok[s]) * DD))[lane];
            ax += v.x; ay += v.y;
        }
        ((float2*)(E + ((size_t)t * BM + wid) * DD))[lane] = make_float2(ax, ay);
    }
}

// One full hop per block (block = one batch element b, 1024 threads = 16 waves):
//   phase 1: logit[m] = dot(E_h[b,m,:], u[b,:])     (wave w -> m in [32w, 32w+32))
//   phase 2: softmax over m in LDS
//   phase 3: o = sum_m prob[m] * E_{h+1}[b,m,:];  u[b] += o
__global__ __launch_bounds__(1024) void hop_kernel(const float* __restrict__ Eh,
                                                   const float* __restrict__ Eh1,
                                                   float* __restrict__ logit,
                                                   float* __restrict__ u) {
    const int b = blockIdx.x;
    const int tid = threadIdx.x;
    const int w = tid >> 6, lane = tid & 63;

    __shared__ float sl[MM];          // logits -> unnormalized exp
    __shared__ float su[DD];          // u[b]
    __shared__ float red[16];         // cross-wave scalar reduce
    __shared__ float redx[16][64];    // cross-wave vector reduce
    __shared__ float redy[16][64];

    if (tid < DD) su[tid] = u[b * DD + tid];
    __syncthreads();
    const float2 uv = ((const float2*)su)[lane];

    // ---- phase 1: logits ----
    const float* Eb = Eh + (size_t)b * MM * DD;
#pragma unroll 4
    for (int m = w * 32; m < w * 32 + 32; ++m) {
        const float2 e = ((const float2*)(Eb + (size_t)m * DD))[lane];
        float p = e.x * uv.x + e.y * uv.y;
#pragma unroll
        for (int off = 32; off; off >>= 1) p += __shfl_down(p, off, 64);
        if (lane == 0) sl[m] = p;
    }
    __syncthreads();

    if (tid < MM) logit[b * MM + tid] = sl[tid];   // final hop's values are the output

    // ---- phase 2: softmax ----
    float mv = (tid < MM) ? sl[tid] : -1e30f;
#pragma unroll
    for (int off = 32; off; off >>= 1) mv = fmaxf(mv, __shfl_xor(mv, off, 64));
    if (lane == 0) red[w] = mv;
    __syncthreads();
    float mx = red[0];
#pragma unroll
    for (int i = 1; i < 16; ++i) mx = fmaxf(mx, red[i]);
    const float e = (tid < MM) ? expf(sl[tid] - mx) : 0.f;
    __syncthreads();                  // done reading sl/red
    if (tid < MM) sl[tid] = e;
    float sv = e;
#pragma unroll
    for (int off = 32; off; off >>= 1) sv += __shfl_xor(sv, off, 64);
    if (lane == 0) red[w] = sv;
    __syncthreads();
    float S = 0.f;
#pragma unroll
    for (int i = 0; i < 16; ++i) S += red[i];
    const float inv = 1.0f / S;

    // ---- phase 3: o = prob^T E_{h+1}[b];  u[b] += o ----
    const float* E1b = Eh1 + (size_t)b * MM * DD;
    float ox = 0.f, oy = 0.f;
#pragma unroll 4
    for (int m = w * 32; m < w * 32 + 32; ++m) {
        const float2 v = ((const float2*)(E1b + (size_t)m * DD))[lane];
        const float pm = sl[m] * inv;
        ox += pm * v.x; oy += pm * v.y;
    }
    redx[w][lane] = ox;
    redy[w][lane] = oy;
    __syncthreads();
    if (w == 0) {
        float sx = 0.f, sy = 0.f;
#pragma unroll
        for (int i = 0; i < 16; ++i) { sx += redx[i][lane]; sy += redy[i][lane]; }
        const float2 uo = ((const float2*)su)[lane];
        ((float2*)(u + b * DD))[lane] = make_float2(uo.x + sx, uo.y + sy);
    }
}

// ====================== FALLBACK PATH (round-1, known-good) ======================
__global__ __launch_bounds__(256) void init_u(const float* __restrict__ hidden,
                                              float* __restrict__ u) {
    int i = blockIdx.x * 256 + threadIdx.x;
    if (i < BB * DD) u[i] = hidden[i];
}

__global__ __launch_bounds__(256) void logit_kernel(const int* __restrict__ story,
                                                    const float* __restrict__ Ch,
                                                    const float* __restrict__ u,
                                                    float* __restrict__ logit) {
    int wid = (blockIdx.x * 256 + threadIdx.x) >> 6;
    int lane = threadIdx.x & 63;
    if (wid >= BB * MM) return;
    int b = wid >> 9;
    const int* st = story + (size_t)wid * SS;
    int tok[SS];
#pragma unroll
    for (int s = 0; s < SS; ++s) tok[s] = st[s];
    float ax = 0.f, ay = 0.f;
#pragma unroll
    for (int s = 0; s < SS; ++s) {
        const float2 v = ((const float2*)(Ch + (size_t)tok[s] * DD))[lane];
        ax += v.x; ay += v.y;
    }
    const float2 uv = ((const float2*)(u + b * DD))[lane];
    float p = ax * uv.x + ay * uv.y;
#pragma unroll
    for (int off = 32; off; off >>= 1) p += __shfl_down(p, off, 64);
    if (lane == 0) logit[wid] = p;
}

__global__ __launch_bounds__(256) void softmax_kernel(const float* __restrict__ logit,
                                                      float* __restrict__ prob) {
    int b = blockIdx.x;
    int t = threadIdx.x;
    __shared__ float red[8];
    float l0 = logit[b * MM + t];
    float l1 = logit[b * MM + 256 + t];
    float mx = fmaxf(l0, l1);
#pragma unroll
    for (int off = 32; off; off >>= 1) mx = fmaxf(mx, __shfl_xor(mx, off, 64));
    if ((t & 63) == 0) red[t >> 6] = mx;
    __syncthreads();
    mx = fmaxf(fmaxf(red[0], red[1]), fmaxf(red[2], red[3]));
    float e0 = expf(l0 - mx), e1 = expf(l1 - mx);
    float s = e0 + e1;
#pragma unroll
    for (int off = 32; off; off >>= 1) s += __shfl_xor(s, off, 64);
    if ((t & 63) == 0) red[4 + (t >> 6)] = s;
    __syncthreads();
    s = red[4] + red[5] + red[6] + red[7];
    float inv = 1.0f / s;
    prob[b * MM + t] = e0 * inv;
    prob[b * MM + 256 + t] = e1 * inv;
}

__global__ __launch_bounds__(256) void partial_kernel(const int* __restrict__ story,
                                                      const float* __restrict__ Ch1,
                                                      const float* __restrict__ prob,
                                                      float* __restrict__ partial,
                                                      int chunk) {
    int b = blockIdx.y, c = blockIdx.x;
    int w = threadIdx.x >> 6, lane = threadIdx.x & 63;
    int m0 = c * chunk;
    float ax = 0.f, ay = 0.f;
    for (int m = m0 + w; m < m0 + chunk; m += 4) {
        float pw = prob[b * MM + m];
        const int* st = story + (size_t)(b * MM + m) * SS;
        int tok[SS];
#pragma unroll
        for (int s = 0; s < SS; ++s) tok[s] = st[s];
        float sx = 0.f, sy = 0.f;
#pragma unroll
        for (int s = 0; s < SS; ++s) {
            const float2 v = ((const float2*)(Ch1 + (size_t)tok[s] * DD))[lane];
            sx += v.x; sy += v.y;
        }
        ax += pw * sx; ay += pw * sy;
    }
    __shared__ float redx[4][64];
    __shared__ float redy[4][64];
    redx[w][lane] = ax;
    redy[w][lane] = ay;
    __syncthreads();
    if (w == 0) {
        float ox = redx[0][lane] + redx[1][lane] + redx[2][lane] + redx[3][lane];
        float oy = redy[0][lane] + redy[1][lane] + redy[2][lane] + redy[3][lane];
        float2* dst = (float2*)(partial + ((size_t)b * gridDim.x + c) * DD);
        dst[lane] = make_float2(ox, oy);
    }
}

__global__ __launch_bounds__(256) void update_kernel(const float* __restrict__ partial,
                                                     float* __restrict__ u, int NC) {
    int i = blockIdx.x * 256 + threadIdx.x;
    if (i >= BB * DD) return;
    int b = i >> 7, d = i & 127;
    float s = 0.f;
    for (int c = 0; c < NC; ++c) s += partial[((size_t)b * NC + c) * DD + d];
    u[i] += s;
}

extern "C" void kernel_launch(void* const* d_in, const int* in_sizes, int n_in,
                              void* d_out, int out_size, void* d_ws, size_t ws_size,
                              hipStream_t stream) {
    const int*   story  = (const int*)d_in[0];
    const float* hidden = (const float*)d_in[1];
    const float* Cmat   = (const float*)d_in[2];

    float* out   = (float*)d_out;
    float* logit = out;              // final prob_logit [B,M]
    float* u     = out + BB * MM;    // final u [B,D]

    const size_t needE = (size_t)(HOPS + 1) * BM * DD * sizeof(float);
    if (ws_size >= needE) {
        float* E = (float*)d_ws;     // [4][BM][DD]
        precompute_E<<<BM / 4, 256, 0, stream>>>(story, Cmat, E, hidden, u);
        for (int h = 0; h < HOPS; ++h) {
            hop_kernel<<<BB, 1024, 0, stream>>>(E + (size_t)h * BM * DD,
                                                E + (size_t)(h + 1) * BM * DD,
                                                logit, u);
        }
    } else {
        float* prob = (float*)d_ws;
        int NC = 32;
        while (NC > 1 && (size_t)(BB * MM + BB * NC * DD) * 4 > ws_size) NC >>= 1;
        float* partial = prob + BB * MM;
        int chunk = MM / NC;

        init_u<<<(BB * DD + 255) / 256, 256, 0, stream>>>(hidden, u);
        for (int h = 0; h < HOPS; ++h) {
            const float* Ca = Cmat + (size_t)h * VV * DD;
            const float* Cc = Cmat + (size_t)(h + 1) * VV * DD;
            logit_kernel<<<(BB * MM) / 4, 256, 0, stream>>>(story, Ca, u, logit);
            softmax_kernel<<<BB, 256, 0, stream>>>(logit, prob);
            partial_kernel<<<dim3(NC, BB), 256, 0, stream>>>(story, Cc, prob, partial, chunk);
            update_kernel<<<(BB * DD + 255) / 256, 256, 0, stream>>>(partial, u, NC);
        }
    }
}

// Round 3
// 67.041 us; speedup vs baseline: 1.7113x; 1.7113x over previous
//
#include <hip/hip_runtime.h>

#define BB 32
#define MM 512
#define SS 10
#define VV 32000
#define DD 128
#define HOPS 3
#define BM (BB * MM)
#define NCHUNK 32          // chunks per b in hop kernels
#define CHM (MM / NCHUNK)  // 16 m per chunk -> 4 m per wave
#define PSTRIDE 132        // partial row: 128 num + 1 den + pad (16B-aligned)

// ====================== PRIMARY PATH ======================

// E[t-1][bm][d] = sum_s C[t][story[bm][s]][d] for t = 1,2 (tables used twice).
// t on blockIdx.y (slow dispatch axis) -> rough temporal phasing per table.
__global__ __launch_bounds__(256) void precompute_E12(const int* __restrict__ story,
                                                      const float* __restrict__ C,
                                                      float* __restrict__ E) {
    const int wid = (blockIdx.x * 256 + threadIdx.x) >> 6;   // 0 .. BM-1
    const int lane = threadIdx.x & 63;
    const int t = blockIdx.y + 1;                            // table 1 or 2
    const int* st = story + (size_t)wid * SS;
    int tok[SS];
#pragma unroll
    for (int s = 0; s < SS; ++s) tok[s] = st[s];
    const float* Ct = C + (size_t)t * VV * DD;
    float ax = 0.f, ay = 0.f;
#pragma unroll
    for (int s = 0; s < SS; ++s) {
        const float2 v = ((const float2*)(Ct + (size_t)tok[s] * DD))[lane];
        ax += v.x; ay += v.y;
    }
    ((float2*)(E + ((size_t)(t - 1) * BM + wid) * DD))[lane] = make_float2(ax, ay);
}

// One hop chunk per block. Max-free softmax: partial num[d] = sum_m exp(l_m)*out_m[d],
// partial den = sum_m exp(l_m). u for this hop is rebuilt in-block from uprev + pin.
// HOP 0: logits gather C0, out = E1, uprev = hidden (no pin)
// HOP 1: logits = E1, out = E2, u = hidden + red(P0); block c==0 writes u1
// HOP 2: logits = E2 (write final logit), out gathers C3, u = u1 + red(P1); c==0 writes u2
template <int HOP>
__global__ __launch_bounds__(256) void hop_fused(const int* __restrict__ story,
                                                 const float* __restrict__ Cg,
                                                 const float* __restrict__ Elog,
                                                 const float* __restrict__ Eout,
                                                 const float* __restrict__ uprev,
                                                 const float* __restrict__ pin,
                                                 float* __restrict__ uwrite,
                                                 float* __restrict__ logit,
                                                 float* __restrict__ pout) {
    const int b = blockIdx.y, c = blockIdx.x;
    const int tid = threadIdx.x;
    const int w = tid >> 6, lane = tid & 63;

    __shared__ float su[DD];
    if (tid < DD) {
        float v = uprev[b * DD + tid];
        if (HOP > 0) {
            float num = 0.f, den = 0.f;
            for (int cc = 0; cc < NCHUNK; ++cc) {
                const float* p = pin + ((size_t)b * NCHUNK + cc) * PSTRIDE;
                num += p[tid];
                den += p[DD];
            }
            v += num / den;
            if (c == 0) uwrite[b * DD + tid] = v;
        }
        su[tid] = v;
    }
    __syncthreads();
    const float2 uv = ((const float2*)su)[lane];

    float nx = 0.f, ny = 0.f, den = 0.f;
    for (int k = 0; k < CHM / 4; ++k) {
        const int m = c * CHM + k * 4 + w;
        const int bm = b * MM + m;
        // ---- logit source row ----
        float ex, ey;
        if (HOP == 0) {
            const int* st = story + (size_t)bm * SS;
            int tok[SS];
#pragma unroll
            for (int s = 0; s < SS; ++s) tok[s] = st[s];
            ex = 0.f; ey = 0.f;
#pragma unroll
            for (int s = 0; s < SS; ++s) {
                const float2 v = ((const float2*)(Cg + (size_t)tok[s] * DD))[lane];
                ex += v.x; ey += v.y;
            }
        } else {
            const float2 v = ((const float2*)(Elog + (size_t)bm * DD))[lane];
            ex = v.x; ey = v.y;
        }
        float l = ex * uv.x + ey * uv.y;
#pragma unroll
        for (int off = 32; off; off >>= 1) l += __shfl_xor(l, off, 64);
        if (HOP == 2 && lane == 0) logit[bm] = l;   // final prob_logit
        const float e = expf(l);
        // ---- output source row ----
        float ox, oy;
        if (HOP == 2) {
            const int* st = story + (size_t)bm * SS;
            int tok[SS];
#pragma unroll
            for (int s = 0; s < SS; ++s) tok[s] = st[s];
            ox = 0.f; oy = 0.f;
#pragma unroll
            for (int s = 0; s < SS; ++s) {
                const float2 v = ((const float2*)(Cg + (size_t)tok[s] * DD))[lane];
                ox += v.x; oy += v.y;
            }
        } else {
            const float2 v = ((const float2*)(Eout + (size_t)bm * DD))[lane];
            ox = v.x; oy = v.y;
        }
        nx += e * ox; ny += e * oy; den += e;
    }

    __shared__ float rx[4][64], ry[4][64], rd[4];
    rx[w][lane] = nx; ry[w][lane] = ny;
    if (lane == 0) rd[w] = den;
    __syncthreads();
    if (w == 0) {
        const float sx = rx[0][lane] + rx[1][lane] + rx[2][lane] + rx[3][lane];
        const float sy = ry[0][lane] + ry[1][lane] + ry[2][lane] + ry[3][lane];
        float* prow = pout + ((size_t)b * NCHUNK + c) * PSTRIDE;
        ((float2*)prow)[lane] = make_float2(sx, sy);
        if (lane == 0) prow[DD] = rd[0] + rd[1] + rd[2] + rd[3];
    }
}

// final u = u2 + red(P2)
__global__ __launch_bounds__(128) void final_u(const float* __restrict__ pin,
                                               const float* __restrict__ u2,
                                               float* __restrict__ uout) {
    const int b = blockIdx.x, d = threadIdx.x;
    float num = 0.f, den = 0.f;
    for (int cc = 0; cc < NCHUNK; ++cc) {
        const float* p = pin + ((size_t)b * NCHUNK + cc) * PSTRIDE;
        num += p[d];
        den += p[DD];
    }
    uout[b * DD + d] = u2[b * DD + d] + num / den;
}

// ====================== FALLBACK PATH (round-1, known-good) ======================
__global__ __launch_bounds__(256) void init_u(const float* __restrict__ hidden,
                                              float* __restrict__ u) {
    int i = blockIdx.x * 256 + threadIdx.x;
    if (i < BB * DD) u[i] = hidden[i];
}

__global__ __launch_bounds__(256) void logit_kernel(const int* __restrict__ story,
                                                    const float* __restrict__ Ch,
                                                    const float* __restrict__ u,
                                                    float* __restrict__ logit) {
    int wid = (blockIdx.x * 256 + threadIdx.x) >> 6;
    int lane = threadIdx.x & 63;
    if (wid >= BB * MM) return;
    int b = wid >> 9;
    const int* st = story + (size_t)wid * SS;
    int tok[SS];
#pragma unroll
    for (int s = 0; s < SS; ++s) tok[s] = st[s];
    float ax = 0.f, ay = 0.f;
#pragma unroll
    for (int s = 0; s < SS; ++s) {
        const float2 v = ((const float2*)(Ch + (size_t)tok[s] * DD))[lane];
        ax += v.x; ay += v.y;
    }
    const float2 uv = ((const float2*)(u + b * DD))[lane];
    float p = ax * uv.x + ay * uv.y;
#pragma unroll
    for (int off = 32; off; off >>= 1) p += __shfl_down(p, off, 64);
    if (lane == 0) logit[wid] = p;
}

__global__ __launch_bounds__(256) void softmax_kernel(const float* __restrict__ logit,
                                                      float* __restrict__ prob) {
    int b = blockIdx.x;
    int t = threadIdx.x;
    __shared__ float red[8];
    float l0 = logit[b * MM + t];
    float l1 = logit[b * MM + 256 + t];
    float mx = fmaxf(l0, l1);
#pragma unroll
    for (int off = 32; off; off >>= 1) mx = fmaxf(mx, __shfl_xor(mx, off, 64));
    if ((t & 63) == 0) red[t >> 6] = mx;
    __syncthreads();
    mx = fmaxf(fmaxf(red[0], red[1]), fmaxf(red[2], red[3]));
    float e0 = expf(l0 - mx), e1 = expf(l1 - mx);
    float s = e0 + e1;
#pragma unroll
    for (int off = 32; off; off >>= 1) s += __shfl_xor(s, off, 64);
    if ((t & 63) == 0) red[4 + (t >> 6)] = s;
    __syncthreads();
    s = red[4] + red[5] + red[6] + red[7];
    float inv = 1.0f / s;
    prob[b * MM + t] = e0 * inv;
    prob[b * MM + 256 + t] = e1 * inv;
}

__global__ __launch_bounds__(256) void partial_kernel(const int* __restrict__ story,
                                                      const float* __restrict__ Ch1,
                                                      const float* __restrict__ prob,
                                                      float* __restrict__ partial,
                                                      int chunk) {
    int b = blockIdx.y, c = blockIdx.x;
    int w = threadIdx.x >> 6, lane = threadIdx.x & 63;
    int m0 = c * chunk;
    float ax = 0.f, ay = 0.f;
    for (int m = m0 + w; m < m0 + chunk; m += 4) {
        float pw = prob[b * MM + m];
        const int* st = story + (size_t)(b * MM + m) * SS;
        int tok[SS];
#pragma unroll
        for (int s = 0; s < SS; ++s) tok[s] = st[s];
        float sx = 0.f, sy = 0.f;
#pragma unroll
        for (int s = 0; s < SS; ++s) {
            const float2 v = ((const float2*)(Ch1 + (size_t)tok[s] * DD))[lane];
            sx += v.x; sy += v.y;
        }
        ax += pw * sx; ay += pw * sy;
    }
    __shared__ float redx[4][64];
    __shared__ float redy[4][64];
    redx[w][lane] = ax;
    redy[w][lane] = ay;
    __syncthreads();
    if (w == 0) {
        float ox = redx[0][lane] + redx[1][lane] + redx[2][lane] + redx[3][lane];
        float oy = redy[0][lane] + redy[1][lane] + redy[2][lane] + redy[3][lane];
        float2* dst = (float2*)(partial + ((size_t)b * gridDim.x + c) * DD);
        dst[lane] = make_float2(ox, oy);
    }
}

__global__ __launch_bounds__(256) void update_kernel(const float* __restrict__ partial,
                                                     float* __restrict__ u, int NC) {
    int i = blockIdx.x * 256 + threadIdx.x;
    if (i >= BB * DD) return;
    int b = i >> 7, d = i & 127;
    float s = 0.f;
    for (int c = 0; c < NC; ++c) s += partial[((size_t)b * NC + c) * DD + d];
    u[i] += s;
}

extern "C" void kernel_launch(void* const* d_in, const int* in_sizes, int n_in,
                              void* d_out, int out_size, void* d_ws, size_t ws_size,
                              hipStream_t stream) {
    const int*   story  = (const int*)d_in[0];
    const float* hidden = (const float*)d_in[1];
    const float* Cmat   = (const float*)d_in[2];

    float* out   = (float*)d_out;
    float* logit = out;              // final prob_logit [B,M]
    float* u     = out + BB * MM;    // final u [B,D]

    // ws layout: E1,E2 | Pa | Pb | u1 | u2
    const size_t szE = (size_t)2 * BM * DD;
    const size_t szP = (size_t)BB * NCHUNK * PSTRIDE;
    const size_t need = (szE + 2 * szP + 2 * BB * DD) * sizeof(float);

    if (ws_size >= need) {
        float* E  = (float*)d_ws;
        float* E1 = E;
        float* E2 = E + (size_t)BM * DD;
        float* Pa = E + szE;
        float* Pb = Pa + szP;
        float* u1 = Pb + szP;
        float* u2 = u1 + BB * DD;
        const float* C0 = Cmat;
        const float* C3 = Cmat + (size_t)3 * VV * DD;

        precompute_E12<<<dim3(BM / 4, 2), 256, 0, stream>>>(story, Cmat, E);
        hop_fused<0><<<dim3(NCHUNK, BB), 256, 0, stream>>>(
            story, C0, nullptr, E1, hidden, nullptr, nullptr, nullptr, Pa);
        hop_fused<1><<<dim3(NCHUNK, BB), 256, 0, stream>>>(
            story, nullptr, E1, E2, hidden, Pa, u1, nullptr, Pb);
        hop_fused<2><<<dim3(NCHUNK, BB), 256, 0, stream>>>(
            story, C3, E2, nullptr, u1, Pb, u2, logit, Pa);
        final_u<<<BB, 128, 0, stream>>>(Pa, u2, u);
    } else {
        float* prob = (float*)d_ws;
        int NC = 32;
        while (NC > 1 && (size_t)(BB * MM + BB * NC * DD) * 4 > ws_size) NC >>= 1;
        float* partial = prob + BB * MM;
        int chunk = MM / NC;

        init_u<<<(BB * DD + 255) / 256, 256, 0, stream>>>(hidden, u);
        for (int h = 0; h < HOPS; ++h) {
            const float* Ca = Cmat + (size_t)h * VV * DD;
            const float* Cc = Cmat + (size_t)(h + 1) * VV * DD;
            logit_kernel<<<(BB * MM) / 4, 256, 0, stream>>>(story, Ca, u, logit);
            softmax_kernel<<<BB, 256, 0, stream>>>(logit, prob);
            partial_kernel<<<dim3(NC, BB), 256, 0, stream>>>(story, Cc, prob, partial, chunk);
            update_kernel<<<(BB * DD + 255) / 256, 256, 0, stream>>>(partial, u, NC);
        }
    }
}